// Round 5
// baseline (106.751 us; speedup 1.0000x reference)
//
#include <hip/hip_runtime.h>

// IDWT3D (haar, tiny): out[T,H,W,c] = x[T/2,H/2,W/2,c] * (1/sqrt2)^3
// x: (16,128,128,64) f32 -> out: (32,256,256,64) f32
//
// R5: wave-contiguous stores. Each thread owns one OUTPUT (W, c4) column
// position for an even (T,H) pair and writes the 4 (T,H)-duplicates.
// Within a wave, lanes cover 64 consecutive output float4 (c4 0..15 x 4
// consecutive W) -> every store instruction is one 1024B linear segment
// (memset-like), instead of 4x256B fragments with gaps.
// Loads: lanes 0-31 / 32-63 share two input rows (wave broadcast, L1 hit).
// Input stays temporal (64 MiB, L3-resident across graph replays);
// stores nontemporal (write-once 512 MiB, no L2/L3 pollution).
//
// Thread index g: c4 = g&15, W = (g>>4)&255, h = (g>>12)&127, t = g>>19
// src  f4 = (t<<18) + (h<<11) + ((W>>1)<<4) + c4
// base f4 = (t<<21) + (h<<13) + (W<<4) + c4   (= output (2t, 2h, W, c4))
// stores: base, base+(1<<12) [H+1], base+(1<<20) [T+1], base+both

typedef float f4 __attribute__((ext_vector_type(4)));

__global__ void idwt3_haar_scatter2(const f4* __restrict__ in,
                                    f4* __restrict__ out,
                                    int total) {
    const float s = 0.35355339059327379f;  // (1/sqrt2)^3
    int idx = blockIdx.x * blockDim.x + threadIdx.x;
    int stride = gridDim.x * blockDim.x;
    for (int g = idx; g < total; g += stride) {
        int c4 = g & 15;
        int W  = (g >> 4) & 255;
        int h  = (g >> 12) & 127;
        int t  = g >> 19;
        int src = (t << 18) + (h << 11) + ((W >> 1) << 4) + c4;
        f4 x = in[src];   // temporal: L3-resident across replays
        x *= s;
        int base = (t << 21) + (h << 13) + (W << 4) + c4;
        f4* p0 = out + base;                         // (2t,   2h,   W)
        f4* p1 = out + base + (1 << 12);             // (2t,   2h+1, W)
        f4* p2 = out + base + (1 << 20);             // (2t+1, 2h,   W)
        f4* p3 = out + base + (1 << 20) + (1 << 12); // (2t+1, 2h+1, W)
        __builtin_nontemporal_store(x, p0);
        __builtin_nontemporal_store(x, p1);
        __builtin_nontemporal_store(x, p2);
        __builtin_nontemporal_store(x, p3);
    }
}

extern "C" void kernel_launch(void* const* d_in, const int* in_sizes, int n_in,
                              void* d_out, int out_size, void* d_ws, size_t ws_size,
                              hipStream_t stream) {
    const f4* in = (const f4*)d_in[0];
    f4* out = (f4*)d_out;
    int total = out_size / 4 / 4;   // 8,388,608 threads (out f4 / 4 dup)
    int block = 256;
    int grid = 4096;                // grid-stride, 8 iters/thread
    idwt3_haar_scatter2<<<grid, block, 0, stream>>>(in, out, total);
}

// Round 6
// 96.906 us; speedup vs baseline: 1.1016x; 1.1016x over previous
//
#include <hip/hip_runtime.h>

// IDWT3D (haar, tiny): out[T,H,W,c] = x[T/2,H/2,W/2,c] * (1/sqrt2)^3
// x: (16,128,128,64) f32 -> out: (32,256,256,64) f32
//
// R6: R4 mapping (1 input f4 -> 8 scatter stores), but with the exactly-8
// grid-stride iterations fully unrolled at compile time: all 8 independent
// loads issue first (one vmcnt wait covers them), then 64 nt stores stream
// back-to-back. Evidence (R1/R4/R5) says we're VMEM-instruction-issue
// limited (~410-450 G instr/s), so maximize issue continuity at the
// minimum instruction count (4.2M loads + 33.5M stores).
// Loads temporal (input 64 MiB = L3-resident across replays); stores
// nontemporal (write-once 512 MiB, don't evict input from L3).
//
// Input  f4 index (t,h,w,c4) = (t<<18) + (h<<11) + (w<<4) + c4
// Output f4 index (T,H,W,c4) = (T<<20) + (H<<12) + (W<<4) + c4

typedef float f4 __attribute__((ext_vector_type(4)));

#define NTHREADS (1 << 19)   // 2048 blocks x 256
#define NIN4     (1 << 22)   // 4,194,304 input float4
#define ITERS    (NIN4 / NTHREADS)  // exactly 8

__global__ void __launch_bounds__(256) idwt3_haar_scatter_u8(
        const f4* __restrict__ in, f4* __restrict__ out) {
    const float s = 0.35355339059327379f;  // (1/sqrt2)^3
    int idx = blockIdx.x * 256 + threadIdx.x;

    f4 x[ITERS];
    int base[ITERS];
#pragma unroll
    for (int k = 0; k < ITERS; ++k) {
        int v = idx + (k << 19);
        x[k] = in[v];                       // 8 independent loads, issued together
        int c4 = v & 15;
        int w  = (v >> 4) & 127;
        int h  = (v >> 11) & 127;
        int t  = v >> 18;
        base[k] = (t << 21) + (h << 13) + (w << 5) + c4;
    }
#pragma unroll
    for (int k = 0; k < ITERS; ++k) {
        f4 y = x[k] * s;
        f4* p0 = out + base[k];                         // (2t,   2h,   2w)
        f4* p1 = out + base[k] + (1 << 12);             // (2t,   2h+1, 2w)
        f4* p2 = out + base[k] + (1 << 20);             // (2t+1, 2h,   2w)
        f4* p3 = out + base[k] + (1 << 20) + (1 << 12); // (2t+1, 2h+1, 2w)
        __builtin_nontemporal_store(y, p0);
        __builtin_nontemporal_store(y, p0 + 16);        // W+1
        __builtin_nontemporal_store(y, p1);
        __builtin_nontemporal_store(y, p1 + 16);
        __builtin_nontemporal_store(y, p2);
        __builtin_nontemporal_store(y, p2 + 16);
        __builtin_nontemporal_store(y, p3);
        __builtin_nontemporal_store(y, p3 + 16);
    }
}

extern "C" void kernel_launch(void* const* d_in, const int* in_sizes, int n_in,
                              void* d_out, int out_size, void* d_ws, size_t ws_size,
                              hipStream_t stream) {
    const f4* in = (const f4*)d_in[0];
    f4* out = (f4*)d_out;
    idwt3_haar_scatter_u8<<<NTHREADS / 256, 256, 0, stream>>>(in, out);
}